// Round 2
// baseline (3271.879 us; speedup 1.0000x reference)
//
#include <hip/hip_runtime.h>
#include <hip/hip_bf16.h>
#include <stdint.h>

#define N_TOKEN 16384
#define N_EMBED 512
#define QBLK 64
#define KVB 32
#define NHALF (N_TOKEN / 2)   // 8192 kv per block
#define NT (NHALF / KVB)      // 256 tiles per block

typedef __attribute__((ext_vector_type(8))) short bf16x8;
typedef __attribute__((ext_vector_type(4))) float f32x4;

__device__ __forceinline__ unsigned short f2bf(float f) {
  unsigned u = __float_as_uint(f);
  u = (u + 0x7FFFu + ((u >> 16) & 1u)) >> 16;
  return (unsigned short)u;
}
__device__ __forceinline__ float bf2f(unsigned short h) {
  return __uint_as_float(((unsigned)h) << 16);
}

__device__ __forceinline__ void load_lds16(const void* g, void* l) {
  __builtin_amdgcn_global_load_lds((const __attribute__((address_space(1))) void*)g,
                                   (__attribute__((address_space(3))) void*)l, 16, 0, 0);
}

// ---------------- prep: f32 -> bf16 (8 elems/thread) ----------------
__global__ void cvt_bf16_kernel(const float* __restrict__ in, unsigned short* __restrict__ out, int n8) {
  int i = blockIdx.x * blockDim.x + threadIdx.x;
  if (i >= n8) return;
  float4 a = ((const float4*)in)[i * 2 + 0];
  float4 b = ((const float4*)in)[i * 2 + 1];
  uint4 o;
  o.x = (unsigned)f2bf(a.x) | ((unsigned)f2bf(a.y) << 16);
  o.y = (unsigned)f2bf(a.z) | ((unsigned)f2bf(a.w) << 16);
  o.z = (unsigned)f2bf(b.x) | ((unsigned)f2bf(b.y) << 16);
  o.w = (unsigned)f2bf(b.z) | ((unsigned)f2bf(b.w) << 16);
  ((uint4*)out)[i] = o;
}

// ---------------- prep: value_w [N][E] f32 -> vt [E][N] bf16 ----------------
__global__ void transpose_cvt_kernel(const float* __restrict__ in, unsigned short* __restrict__ out) {
  __shared__ float tile[64][65];
  int n0 = blockIdx.x * 64;
  int e0 = blockIdx.y * 64;
  int c = threadIdx.x & 63;
  int r0 = threadIdx.x >> 6;
#pragma unroll
  for (int r = r0; r < 64; r += 4)
    tile[r][c] = in[(size_t)(n0 + r) * N_EMBED + e0 + c];
  __syncthreads();
#pragma unroll
  for (int r = r0; r < 64; r += 4)
    out[(size_t)(e0 + r) * N_TOKEN + n0 + c] = f2bf(tile[c][r]);
}

// ---------------- main fused flash kernel (split-N) ----------------
// 512 blocks x 256 threads. Block b: q-rows 64*(b&255), vocab half h=b>>8.
// Wave w = 2*wr + we: QK rows [32wr,32wr+32) x E-slice [256we,256we+256).
// PV: e-slice [128w,128w+128), all 64 rows (pa combined redundantly per wave).
__global__ __launch_bounds__(256, 2) void flash2_kernel(
    const unsigned short* __restrict__ xb,   // [T][512] bf16
    const unsigned short* __restrict__ kb,   // [N][512] bf16 (lin_w)
    const unsigned short* __restrict__ vt,   // [512][N] bf16 (value_w^T)
    const float* __restrict__ bias,          // [N]
    float* __restrict__ Oacc,                // [T][512] f32 accum (zeroed)
    float* __restrict__ lsum)                // [T] f32 accum (zeroed)
{
  __shared__ __align__(16) unsigned char lds[64 * 1024 + 2 * 5120];
  unsigned char* Ks = lds;                 // 2 x 32KB K tile [32][512] bf16, row-swizzled
  unsigned char* Sp = lds + 64 * 1024;     // 2 x [64 rows][80B] bf16 partial logits

  const int tid = threadIdx.x;
  const int w = tid >> 6;
  const int lane = tid & 63;
  const int g = lane >> 4;
  const int l15 = lane & 15;
  const int wr = w >> 1, we = w & 1;
  const int b = blockIdx.x;
  const int qbase = (b & 255) * QBLK;
  const int kv0 = (b >> 8) * NHALF;

  // Q fragments: rows qbase+32wr+16rf+l15, E = 256we + 32kk + 8g
  bf16x8 q[2][8];
#pragma unroll
  for (int rf = 0; rf < 2; ++rf)
#pragma unroll
    for (int kk = 0; kk < 8; ++kk)
      q[rf][kk] = *(const bf16x8*)(xb + (size_t)(qbase + 32 * wr + 16 * rf + l15) * N_EMBED +
                                   256 * we + 32 * kk + 8 * g);

  const f32x4 fzero = {0.f, 0.f, 0.f, 0.f};
  f32x4 acc[4][8];
#pragma unroll
  for (int rf = 0; rf < 4; ++rf)
#pragma unroll
    for (int cf = 0; cf < 8; ++cf) acc[rf][cf] = fzero;
  float lsr[4] = {0.f, 0.f, 0.f, 0.f};

  auto stage = [&](int half, int t) {
    const unsigned char* kg = (const unsigned char*)(kb + (size_t)(kv0 + t * KVB) * N_EMBED);
    unsigned char* Kd = Ks + half * 32768;
#pragma unroll
    for (int it = 0; it < 8; ++it) {
      int c = tid + 256 * it;   // 2048 chunks of 16B
      int row = c >> 6;         // 64 chunks per 1024B row
      int cb = (c & 63) * 16;
      load_lds16(kg + row * 1024 + (cb ^ ((row & 7) << 4)), Kd + c * 16);
    }
  };

  stage(0, 0);

  for (int kt = 0; kt < NT; ++kt) {
    const int buf = kt & 1;
    const unsigned char* Kb = Ks + buf * 32768;

    // ---- V B-fragments direct from global (L2/LLC), issued at tile top
    bf16x8 bv[8];
    {
      const unsigned short* vbase = vt + kv0 + kt * KVB + 8 * g;
#pragma unroll
      for (int cf = 0; cf < 8; ++cf)
        bv[cf] = *(const bf16x8*)(vbase + (size_t)(128 * w + 16 * cf + l15) * N_TOKEN);
    }

    // ---- prefetch next K tile; drain only the CURRENT tile's stage
    if (kt + 1 < NT) {
      stage(buf ^ 1, kt + 1);
      asm volatile("s_waitcnt vmcnt(16)" ::: "memory");  // leaves bv(8)+next stage(8)
    } else {
      asm volatile("s_waitcnt vmcnt(8)" ::: "memory");   // leaves bv(8)
    }
    __builtin_amdgcn_sched_barrier(0);
    __builtin_amdgcn_s_barrier();  // barrier A: K[buf] visible; Sp(kt-1) fully consumed

    // ---- QK^T partial: rows 32wr..+32, E-slice 256we..+256
    f32x4 s[2][2];
#pragma unroll
    for (int rf = 0; rf < 2; ++rf) { s[rf][0] = fzero; s[rf][1] = fzero; }
#pragma unroll
    for (int kk = 0; kk < 8; ++kk) {
      int cb = 512 * we + 64 * kk + 16 * g;
      bf16x8 bk0 = *(const bf16x8*)(Kb + l15 * 1024 + (cb ^ ((l15 & 7) << 4)));
      bf16x8 bk1 = *(const bf16x8*)(Kb + (16 + l15) * 1024 + (cb ^ (((16 + l15) & 7) << 4)));
#pragma unroll
      for (int rf = 0; rf < 2; ++rf) {
        s[rf][0] = __builtin_amdgcn_mfma_f32_16x16x32_bf16(q[rf][kk], bk0, s[rf][0], 0, 0, 0);
        s[rf][1] = __builtin_amdgcn_mfma_f32_16x16x32_bf16(q[rf][kk], bk1, s[rf][1], 0, 0, 0);
      }
    }
    // ---- write bf16 partials: Sp[we][row][kv], row stride 80B (bank-balanced)
#pragma unroll
    for (int rf = 0; rf < 2; ++rf)
#pragma unroll
      for (int nf = 0; nf < 2; ++nf)
#pragma unroll
        for (int j = 0; j < 4; ++j) {
          int row = 32 * wr + 16 * rf + 4 * g + j;
          *(unsigned short*)(Sp + we * 5120 + row * 80 + ((16 * nf + l15) << 1)) =
              f2bf(s[rf][nf][j]);
        }
    asm volatile("s_waitcnt lgkmcnt(0)" ::: "memory");
    __builtin_amdgcn_sched_barrier(0);
    __builtin_amdgcn_s_barrier();  // barrier B: partials visible (vmcnt NOT drained)

    // ---- combine partials + bias, exp (redundant per wave), pa in-register
    bf16x8 pa[4];
    const float* bp = bias + kv0 + kt * KVB + 8 * g;
    float4 b0 = *(const float4*)bp;
    float4 b1 = *(const float4*)(bp + 4);
    float bb[8] = {b0.x, b0.y, b0.z, b0.w, b1.x, b1.y, b1.z, b1.w};
#pragma unroll
    for (int rf = 0; rf < 4; ++rf) {
      int off = (16 * rf + l15) * 80 + 16 * g;
      bf16x8 p0 = *(const bf16x8*)(Sp + off);
      bf16x8 p1 = *(const bf16x8*)(Sp + 5120 + off);
      float ps = 0.f;
#pragma unroll
      for (int i = 0; i < 8; ++i) {
        float v = exp2f((bf2f((unsigned short)p0[i]) + bf2f((unsigned short)p1[i]) + bb[i]) *
                        1.44269504f);
        pa[rf][i] = (short)f2bf(v);
        ps += v;
      }
      lsr[rf] += ps;
    }
    // ---- PV: O[64 x 128w..] += P * V
#pragma unroll
    for (int cf = 0; cf < 8; ++cf)
#pragma unroll
      for (int rf = 0; rf < 4; ++rf)
        acc[rf][cf] = __builtin_amdgcn_mfma_f32_16x16x32_bf16(pa[rf], bv[cf], acc[rf][cf], 0, 0, 0);
  }

  // ---- epilogue: atomically accumulate un-normalized O and row sums
#pragma unroll
  for (int rf = 0; rf < 4; ++rf) {
    float r = lsr[rf];
    r += __shfl_xor(r, 16, 64);
    r += __shfl_xor(r, 32, 64);
    if (w == 0 && g == 0) atomicAdd(&lsum[qbase + 16 * rf + l15], r);
#pragma unroll
    for (int cf = 0; cf < 8; ++cf)
#pragma unroll
      for (int j = 0; j < 4; ++j) {
        int row = qbase + 16 * rf + 4 * g + j;
        int col = 128 * w + 16 * cf + l15;
        atomicAdd(&Oacc[(size_t)row * N_EMBED + col], acc[rf][cf][j]);
      }
  }
}

// ---------------- normalize + residual ----------------
__global__ void norm_kernel(float* __restrict__ Oacc, const float* __restrict__ lsum,
                            const float* __restrict__ x) {
  const int n4 = (N_TOKEN * N_EMBED) / 4;
  for (int i = blockIdx.x * blockDim.x + threadIdx.x; i < n4; i += gridDim.x * blockDim.x) {
    float4 o = ((const float4*)Oacc)[i];
    float inv = 1.0f / lsum[i >> 7];  // (i*4)/512
    float4 xi = ((const float4*)x)[i];
    o.x = o.x * inv + xi.x;
    o.y = o.y * inv + xi.y;
    o.z = o.z * inv + xi.z;
    o.w = o.w * inv + xi.w;
    ((float4*)Oacc)[i] = o;
  }
}

extern "C" void kernel_launch(void* const* d_in, const int* in_sizes, int n_in,
                              void* d_out, int out_size, void* d_ws, size_t ws_size,
                              hipStream_t stream) {
  const float* x = (const float*)d_in[0];        // [8,2048,512] f32
  const float* lin_w = (const float*)d_in[1];    // [16384,512] f32
  const float* lin_b = (const float*)d_in[2];    // [16384] f32
  const float* value_w = (const float*)d_in[3];  // [16384,512] f32
  float* outp = (float*)d_out;

  unsigned short* xb = (unsigned short*)d_ws;                        // 16MB
  unsigned short* wb = (unsigned short*)((char*)d_ws + (16 << 20));  // 16MB
  unsigned short* vt = (unsigned short*)((char*)d_ws + (32 << 20));  // 16MB
  float* lsum = (float*)((char*)d_ws + (48 << 20));                  // 64KB

  hipMemsetAsync(d_out, 0, (size_t)N_TOKEN * N_EMBED * sizeof(float), stream);
  hipMemsetAsync(lsum, 0, (size_t)N_TOKEN * sizeof(float), stream);

  const int n8 = (N_TOKEN * N_EMBED) / 8;  // 1048576
  cvt_bf16_kernel<<<n8 / 256, 256, 0, stream>>>(x, xb, n8);
  cvt_bf16_kernel<<<n8 / 256, 256, 0, stream>>>(lin_w, wb, n8);
  transpose_cvt_kernel<<<dim3(N_TOKEN / 64, N_EMBED / 64), 256, 0, stream>>>(value_w, vt);
  flash2_kernel<<<512, 256, 0, stream>>>(xb, wb, vt, lin_b, outp, lsum);
  norm_kernel<<<2048, 256, 0, stream>>>(outp, lsum, x);
}

// Round 3
// 1215.609 us; speedup vs baseline: 2.6916x; 2.6916x over previous
//
#include <hip/hip_runtime.h>
#include <hip/hip_bf16.h>
#include <stdint.h>

#define N_TOKEN 16384
#define N_EMBED 512
#define QBLK 64
#define KVB 64
#define NT (N_TOKEN / KVB)   // 256 tiles

typedef __attribute__((ext_vector_type(8))) short bf16x8;
typedef __attribute__((ext_vector_type(4))) float f32x4;

__device__ __forceinline__ unsigned short f2bf(float f) {
  unsigned u = __float_as_uint(f);
  u = (u + 0x7FFFu + ((u >> 16) & 1u)) >> 16;
  return (unsigned short)u;
}
__device__ __forceinline__ float bf2f(unsigned short h) {
  return __uint_as_float(((unsigned)h) << 16);
}

__device__ __forceinline__ void load_lds16(const void* g, void* l) {
  __builtin_amdgcn_global_load_lds((const __attribute__((address_space(1))) void*)g,
                                   (__attribute__((address_space(3))) void*)l, 16, 0, 0);
}

// ---------------- prep: f32 -> bf16 (8 elems/thread) ----------------
__global__ void cvt_bf16_kernel(const float* __restrict__ in, unsigned short* __restrict__ out, int n8) {
  int i = blockIdx.x * blockDim.x + threadIdx.x;
  if (i >= n8) return;
  float4 a = ((const float4*)in)[i * 2 + 0];
  float4 b = ((const float4*)in)[i * 2 + 1];
  uint4 o;
  o.x = (unsigned)f2bf(a.x) | ((unsigned)f2bf(a.y) << 16);
  o.y = (unsigned)f2bf(a.z) | ((unsigned)f2bf(a.w) << 16);
  o.z = (unsigned)f2bf(b.x) | ((unsigned)f2bf(b.y) << 16);
  o.w = (unsigned)f2bf(b.z) | ((unsigned)f2bf(b.w) << 16);
  ((uint4*)out)[i] = o;
}

// ---------------- prep: value_w [N][E] f32 -> vt [E][N] bf16 ----------------
__global__ void transpose_cvt_kernel(const float* __restrict__ in, unsigned short* __restrict__ out) {
  __shared__ float tile[64][65];
  int n0 = blockIdx.x * 64;
  int e0 = blockIdx.y * 64;
  int c = threadIdx.x & 63;
  int r0 = threadIdx.x >> 6;
#pragma unroll
  for (int r = r0; r < 64; r += 4)
    tile[r][c] = in[(size_t)(n0 + r) * N_EMBED + e0 + c];
  __syncthreads();
#pragma unroll
  for (int r = r0; r < 64; r += 4)
    out[(size_t)(e0 + r) * N_TOKEN + n0 + c] = f2bf(tile[c][r]);
}

// ---------------- main fused flash kernel ----------------
// 256 blocks x 512 threads (8 waves). Block = 64 q-rows, sweeps ALL 16384 kv
// (identical tile sequence across blocks -> L2-synchronized sharing).
// QK: wave w=(wr=w>>1, we=w&1): q-rows [16wr,16wr+16) x E-half [256we,+256).
// exp: wave w owns rows [8w, 8w+8). PV: wave w owns e-cols [64w, 64w+64).
__global__ __launch_bounds__(512, 2) void flash3_kernel(
    const unsigned short* __restrict__ xb,   // [T][512] bf16
    const unsigned short* __restrict__ kb,   // [N][512] bf16 (lin_w)
    const unsigned short* __restrict__ vt,   // [512][N] bf16 (value_w^T)
    const float* __restrict__ bias,          // [N]
    const float* __restrict__ xf,            // [T][512] f32 (residual)
    float* __restrict__ out)                 // [T][512] f32
{
  __shared__ __align__(16) unsigned char lds[131072 + 16384 + 8192 + 256];
  unsigned char* Ks = lds;                   // 2 x 64KB K tile [64][512] bf16, slot-swizzled
  unsigned char* Sp = lds + 131072;          // [2 we][64 row][64 kv] bf16, slot-swizzled
  unsigned char* Pb = lds + 131072 + 16384;  // [64 row][64 kv] bf16, slot-swizzled
  float* lsumB = (float*)(lds + 131072 + 16384 + 8192);  // [64]

  const int tid = threadIdx.x;
  const int w = tid >> 6;
  const int lane = tid & 63;
  const int g = lane >> 4;
  const int l15 = lane & 15;
  const int wr = w >> 1, we = w & 1;
  const int qbase = blockIdx.x * QBLK;

  if (tid < 64) lsumB[tid] = 0.f;

  // Q fragments: rows qbase+16wr+l15, E = 256we + 32kk + 8g
  bf16x8 q[8];
#pragma unroll
  for (int kk = 0; kk < 8; ++kk)
    q[kk] = *(const bf16x8*)(xb + (size_t)(qbase + 16 * wr + l15) * N_EMBED + 256 * we + 32 * kk + 8 * g);

  const f32x4 fzero = {0.f, 0.f, 0.f, 0.f};
  f32x4 acc[4][4];
#pragma unroll
  for (int rf = 0; rf < 4; ++rf)
#pragma unroll
    for (int cf = 0; cf < 4; ++cf) acc[rf][cf] = fzero;

  auto stage = [&](int half, int t) {
    const unsigned char* kg = (const unsigned char*)(kb + (size_t)t * KVB * N_EMBED);
    unsigned char* Kd = Ks + half * 65536;
#pragma unroll
    for (int it = 0; it < 8; ++it) {
      int c = tid + 512 * it;   // 4096 chunks of 16B
      int row = c >> 6;         // 64 chunks per 1024B row
      int cb = (c & 63) * 16;
      // linear LDS dest; inverse(=same, involution) swizzle on global source
      load_lds16(kg + row * 1024 + (cb ^ ((row & 7) << 4)), Kd + c * 16);
    }
  };

  stage(0, 0);

  for (int kt = 0; kt < NT; ++kt) {
    const int buf = kt & 1;
    const unsigned char* Kb = Ks + buf * 65536;

    // ---- V B-fragments direct from global (L2), issued at tile top
    bf16x8 bv[4][2];
    {
      const unsigned short* vbase = vt + kt * KVB + 8 * g;
#pragma unroll
      for (int cf = 0; cf < 4; ++cf)
#pragma unroll
        for (int ks = 0; ks < 2; ++ks)
          bv[cf][ks] = *(const bf16x8*)(vbase + (size_t)(64 * w + 16 * cf + l15) * N_TOKEN + 32 * ks);
    }

    // ---- prefetch next K tile; drain only the previous tile's stage
    if (kt + 1 < NT) {
      stage(buf ^ 1, kt + 1);
      asm volatile("s_waitcnt vmcnt(16)" ::: "memory");  // keeps bv(8)+next stage(8) in flight
    } else {
      asm volatile("s_waitcnt vmcnt(8)" ::: "memory");   // keeps bv(8)
    }
    __builtin_amdgcn_sched_barrier(0);
    __builtin_amdgcn_s_barrier();  // A: K[buf] visible everywhere

    // ---- QK^T partial: rows [16wr,+16) x kv[64], E-half [256we,+256)
    f32x4 s[4];
#pragma unroll
    for (int nf = 0; nf < 4; ++nf) s[nf] = fzero;
    __builtin_amdgcn_s_setprio(1);
#pragma unroll
    for (int kk = 0; kk < 8; ++kk) {
      int cb = 512 * we + 64 * kk + 16 * g;
#pragma unroll
      for (int nf = 0; nf < 4; ++nf) {
        int row = 16 * nf + l15;  // kv row
        bf16x8 bk = *(const bf16x8*)(Kb + row * 1024 + (cb ^ ((row & 7) << 4)));
        s[nf] = __builtin_amdgcn_mfma_f32_16x16x32_bf16(q[kk], bk, s[nf], 0, 0, 0);
      }
    }
    __builtin_amdgcn_s_setprio(0);
    // ---- write bf16 partials, slot-swizzled: slot = (kvbyte>>4) ^ (row&7)
#pragma unroll
    for (int nf = 0; nf < 4; ++nf)
#pragma unroll
      for (int j = 0; j < 4; ++j) {
        int row = 16 * wr + 4 * g + j;
        int slot = (2 * nf + (l15 >> 3)) ^ (row & 7);
        *(unsigned short*)(Sp + we * 8192 + row * 128 + 16 * slot + 2 * (l15 & 7)) = f2bf(s[nf][j]);
      }
    asm volatile("s_waitcnt lgkmcnt(0)" ::: "memory");
    __builtin_amdgcn_sched_barrier(0);
    __builtin_amdgcn_s_barrier();  // B: partials visible

    // ---- wave w: rows [8w,8w+8): combine halves + bias, exp, write P, row sums
    {
      int row = 8 * w + (lane >> 3);
      int c = lane & 7;
      int off = row * 128 + 16 * (c ^ (row & 7));
      bf16x8 p0 = *(const bf16x8*)(Sp + off);
      bf16x8 p1 = *(const bf16x8*)(Sp + 8192 + off);
      const float* bp = bias + kt * KVB + 8 * c;
      float4 b0 = *(const float4*)bp;
      float4 b1 = *(const float4*)(bp + 4);
      float bb[8] = {b0.x, b0.y, b0.z, b0.w, b1.x, b1.y, b1.z, b1.w};
      bf16x8 pw;
      float ps = 0.f;
#pragma unroll
      for (int i = 0; i < 8; ++i) {
        float v = exp2f((bf2f((unsigned short)p0[i]) + bf2f((unsigned short)p1[i]) + bb[i]) * 1.44269504f);
        pw[i] = (short)f2bf(v);
        ps += v;
      }
      *(bf16x8*)(Pb + off) = pw;
      ps += __shfl_xor(ps, 1, 64);
      ps += __shfl_xor(ps, 2, 64);
      ps += __shfl_xor(ps, 4, 64);
      if (c == 0) lsumB[row] += ps;
    }
    asm volatile("s_waitcnt lgkmcnt(0)" ::: "memory");
    __builtin_amdgcn_sched_barrier(0);
    __builtin_amdgcn_s_barrier();  // C: P visible

    // ---- PV: O[64 rows x e 64w..+64] += P * V
    __builtin_amdgcn_s_setprio(1);
#pragma unroll
    for (int ks = 0; ks < 2; ++ks) {
      bf16x8 pa[4];
#pragma unroll
      for (int rf = 0; rf < 4; ++rf) {
        int row = 16 * rf + l15;
        pa[rf] = *(const bf16x8*)(Pb + row * 128 + 16 * ((4 * ks + g) ^ (row & 7)));
      }
#pragma unroll
      for (int cf = 0; cf < 4; ++cf)
#pragma unroll
        for (int rf = 0; rf < 4; ++rf)
          acc[rf][cf] = __builtin_amdgcn_mfma_f32_16x16x32_bf16(pa[rf], bv[cf][ks], acc[rf][cf], 0, 0, 0);
    }
    __builtin_amdgcn_s_setprio(0);
  }

  // ---- epilogue: out = acc/lsum + x  (each block owns its 64 rows)
#pragma unroll
  for (int rf = 0; rf < 4; ++rf)
#pragma unroll
    for (int j = 0; j < 4; ++j) {
      int lrow = 16 * rf + 4 * g + j;
      float inv = 1.0f / lsumB[lrow];
      int row = qbase + lrow;
#pragma unroll
      for (int cf = 0; cf < 4; ++cf) {
        int col = 64 * w + 16 * cf + l15;
        size_t idx = (size_t)row * N_EMBED + col;
        out[idx] = acc[rf][cf][j] * inv + xf[idx];
      }
    }
}

extern "C" void kernel_launch(void* const* d_in, const int* in_sizes, int n_in,
                              void* d_out, int out_size, void* d_ws, size_t ws_size,
                              hipStream_t stream) {
  const float* x = (const float*)d_in[0];        // [8,2048,512] f32
  const float* lin_w = (const float*)d_in[1];    // [16384,512] f32
  const float* lin_b = (const float*)d_in[2];    // [16384] f32
  const float* value_w = (const float*)d_in[3];  // [16384,512] f32
  float* outp = (float*)d_out;

  unsigned short* xb = (unsigned short*)d_ws;                        // 16MB
  unsigned short* wb = (unsigned short*)((char*)d_ws + (16 << 20));  // 16MB
  unsigned short* vt = (unsigned short*)((char*)d_ws + (32 << 20));  // 16MB

  const int n8 = (N_TOKEN * N_EMBED) / 8;  // 1048576
  cvt_bf16_kernel<<<n8 / 256, 256, 0, stream>>>(x, xb, n8);
  cvt_bf16_kernel<<<n8 / 256, 256, 0, stream>>>(lin_w, wb, n8);
  transpose_cvt_kernel<<<dim3(N_TOKEN / 64, N_EMBED / 64), 256, 0, stream>>>(value_w, vt);
  flash3_kernel<<<N_TOKEN / QBLK, 512, 0, stream>>>(xb, wb, vt, lin_b, x, outp);
}

// Round 4
// 1076.027 us; speedup vs baseline: 3.0407x; 1.1297x over previous
//
#include <hip/hip_runtime.h>
#include <hip/hip_bf16.h>
#include <stdint.h>

#define N_TOKEN 16384
#define N_EMBED 512
#define QBLK 64
#define KVB 32
#define NT (N_TOKEN / KVB)   // 512 tiles

typedef __attribute__((ext_vector_type(8))) short bf16x8;
typedef __attribute__((ext_vector_type(4))) short bf16x4;
typedef __attribute__((ext_vector_type(4))) float f32x4;

__device__ __forceinline__ unsigned short f2bf(float f) {
  unsigned u = __float_as_uint(f);
  u = (u + 0x7FFFu + ((u >> 16) & 1u)) >> 16;
  return (unsigned short)u;
}
__device__ __forceinline__ float bf2f(unsigned short h) {
  return __uint_as_float(((unsigned)h) << 16);
}

__device__ __forceinline__ void load_lds16(const void* g, void* l) {
  __builtin_amdgcn_global_load_lds((const __attribute__((address_space(1))) void*)g,
                                   (__attribute__((address_space(3))) void*)l, 16, 0, 0);
}

// ---------------- prep: f32 -> bf16 (8 elems/thread) ----------------
__global__ void cvt_bf16_kernel(const float* __restrict__ in, unsigned short* __restrict__ out, int n8) {
  int i = blockIdx.x * blockDim.x + threadIdx.x;
  if (i >= n8) return;
  float4 a = ((const float4*)in)[i * 2 + 0];
  float4 b = ((const float4*)in)[i * 2 + 1];
  uint4 o;
  o.x = (unsigned)f2bf(a.x) | ((unsigned)f2bf(a.y) << 16);
  o.y = (unsigned)f2bf(a.z) | ((unsigned)f2bf(a.w) << 16);
  o.z = (unsigned)f2bf(b.x) | ((unsigned)f2bf(b.y) << 16);
  o.w = (unsigned)f2bf(b.z) | ((unsigned)f2bf(b.w) << 16);
  ((uint4*)out)[i] = o;
}

// ---------------- prep: value_w [N][E] f32 -> vt [E][N] bf16 ----------------
__global__ void transpose_cvt_kernel(const float* __restrict__ in, unsigned short* __restrict__ out) {
  __shared__ float tile[64][65];
  int n0 = blockIdx.x * 64;
  int e0 = blockIdx.y * 64;
  int c = threadIdx.x & 63;
  int r0 = threadIdx.x >> 6;
#pragma unroll
  for (int r = r0; r < 64; r += 4)
    tile[r][c] = in[(size_t)(n0 + r) * N_EMBED + e0 + c];
  __syncthreads();
#pragma unroll
  for (int r = r0; r < 64; r += 4)
    out[(size_t)(e0 + r) * N_TOKEN + n0 + c] = f2bf(tile[c][r]);
}

// ---------------- main fused flash kernel, 1-barrier 3-stage pipeline ----------------
// 256 blocks x 512 threads. Region t: QK(t) || exp(t-1) || PV(t-2) || stage(t+1).
// QK: wave (we=w>>1: E-128 slice, wn=w&1: kv-16 slice), rf=4 (all 64 rows).
// exp: wave w owns q-rows [8w,8w+8). PV: wave w owns e-slice [64w,64w+64).
__global__ __launch_bounds__(512, 1) void flash4_kernel(
    const unsigned short* __restrict__ xb,   // [T][512] bf16
    const unsigned short* __restrict__ kb,   // [N][512] bf16 (lin_w)
    const unsigned short* __restrict__ vt,   // [512][N] bf16 (value_w^T)
    const float* __restrict__ bias,          // [N]
    const float* __restrict__ xf,            // [T][512] f32 (residual)
    float* __restrict__ out)                 // [T][512] f32
{
  // K: 2 x 32KB; Sp: 2 x [4 we][64 q][72B]; Pb: 2 x [64 q][64B]; lsumB: 64 f32
  __shared__ __align__(16) unsigned char lds[65536 + 36864 + 8192 + 256];
  unsigned char* Ks = lds;
  unsigned char* Sp = lds + 65536;
  unsigned char* Pb = lds + 65536 + 36864;
  float* lsumB = (float*)(lds + 65536 + 36864 + 8192);

  const int tid = threadIdx.x;
  const int w = tid >> 6;
  const int lane = tid & 63;
  const int g = lane >> 4;
  const int l15 = lane & 15;
  const int we = w >> 1, wn = w & 1;
  const int qbase = blockIdx.x * QBLK;

  // Q fragments: q[rf][kk] rows qbase+16rf+l15, E = 128we + 32kk + 8g
  bf16x8 q[4][4];
#pragma unroll
  for (int rf = 0; rf < 4; ++rf)
#pragma unroll
    for (int kk = 0; kk < 4; ++kk)
      q[rf][kk] = *(const bf16x8*)(xb + (size_t)(qbase + 16 * rf + l15) * N_EMBED +
                                   128 * we + 32 * kk + 8 * g);

  const f32x4 fzero = {0.f, 0.f, 0.f, 0.f};
  f32x4 acc[4][4];
#pragma unroll
  for (int rf = 0; rf < 4; ++rf)
#pragma unroll
    for (int cf = 0; cf < 4; ++cf) acc[rf][cf] = fzero;
  float lsum_reg = 0.f;

  // exp-phase lane mapping
  const int eq = 8 * w + (lane >> 3);  // q-row this lane combines
  const int ec = lane & 7;             // kv-quarter (4 kv per lane)

  auto stage = [&](int half, int t) {
    const unsigned char* kg = (const unsigned char*)(kb + (size_t)t * KVB * N_EMBED);
    unsigned char* Kd = Ks + half * 32768;
#pragma unroll
    for (int it = 0; it < 4; ++it) {
      int c = tid + 512 * it;   // 2048 chunks of 16B
      int row = c >> 6;         // 64 chunks per 1024B row
      int cb = (c & 63) * 16;
      load_lds16(kg + row * 1024 + (cb ^ ((row & 7) << 4)), Kd + c * 16);
    }
  };

  stage(0, 0);

  for (int t = 0; t < NT + 2; ++t) {
    asm volatile("s_waitcnt vmcnt(0) lgkmcnt(0)" ::: "memory");
    __builtin_amdgcn_sched_barrier(0);
    __builtin_amdgcn_s_barrier();

    // ---- issue bv loads for PV(t-2) FIRST (so bv-wait never drains stage)
    bf16x8 bv[4];
    if (t >= 2) {
      const unsigned short* vbase = vt + (size_t)(t - 2) * KVB + 8 * g;
#pragma unroll
      for (int cf = 0; cf < 4; ++cf)
        bv[cf] = *(const bf16x8*)(vbase + (size_t)(64 * w + 16 * cf + l15) * N_TOKEN);
    }
    // ---- issue stage of K(t+1)
    if (t + 1 < NT) stage((t + 1) & 1, t + 1);

    // ---- QK(t): rows 64 (rf=4) x kv [16wn,+16) x E [128we,+128)
    if (t < NT) {
      const unsigned char* Kb = Ks + (t & 1) * 32768;
      f32x4 s[4];
#pragma unroll
      for (int rf = 0; rf < 4; ++rf) s[rf] = fzero;
      const int krow = 16 * wn + l15;
      __builtin_amdgcn_s_setprio(1);
#pragma unroll
      for (int kk = 0; kk < 4; ++kk) {
        int cb = 256 * we + 64 * kk + 16 * g;
        bf16x8 bk = *(const bf16x8*)(Kb + krow * 1024 + (cb ^ ((krow & 7) << 4)));
#pragma unroll
        for (int rf = 0; rf < 4; ++rf)
          s[rf] = __builtin_amdgcn_mfma_f32_16x16x32_bf16(q[rf][kk], bk, s[rf], 0, 0, 0);
      }
      __builtin_amdgcn_s_setprio(0);
      // write partials: Sp[t&1][we][q][kv], row stride 72B (bank-spread)
      unsigned char* sp = Sp + (t & 1) * 18432 + we * 4608;
#pragma unroll
      for (int rf = 0; rf < 4; ++rf)
#pragma unroll
        for (int j = 0; j < 4; ++j) {
          int qq = 16 * rf + 4 * g + j;
          *(unsigned short*)(sp + qq * 72 + (16 * wn + l15) * 2) = f2bf(s[rf][j]);
        }
    }

    // ---- exp(t-1): combine 4 partials + bias, exp, write Pb[(t-1)&1], lsum
    if (t >= 1 && t <= NT) {
      const unsigned char* sp = Sp + ((t - 1) & 1) * 18432;
      int off = eq * 72 + ec * 8;
      bf16x4 p0 = *(const bf16x4*)(sp + off);
      bf16x4 p1 = *(const bf16x4*)(sp + 4608 + off);
      bf16x4 p2 = *(const bf16x4*)(sp + 9216 + off);
      bf16x4 p3 = *(const bf16x4*)(sp + 13824 + off);
      float4 bb = *(const float4*)(bias + (t - 1) * KVB + 4 * ec);
      float l0 = bf2f((unsigned short)p0[0]) + bf2f((unsigned short)p1[0]) +
                 bf2f((unsigned short)p2[0]) + bf2f((unsigned short)p3[0]) + bb.x;
      float l1 = bf2f((unsigned short)p0[1]) + bf2f((unsigned short)p1[1]) +
                 bf2f((unsigned short)p2[1]) + bf2f((unsigned short)p3[1]) + bb.y;
      float l2 = bf2f((unsigned short)p0[2]) + bf2f((unsigned short)p1[2]) +
                 bf2f((unsigned short)p2[2]) + bf2f((unsigned short)p3[2]) + bb.z;
      float l3 = bf2f((unsigned short)p0[3]) + bf2f((unsigned short)p1[3]) +
                 bf2f((unsigned short)p2[3]) + bf2f((unsigned short)p3[3]) + bb.w;
      float e0 = exp2f(l0 * 1.44269504f);
      float e1 = exp2f(l1 * 1.44269504f);
      float e2 = exp2f(l2 * 1.44269504f);
      float e3 = exp2f(l3 * 1.44269504f);
      lsum_reg += (e0 + e1) + (e2 + e3);
      bf16x4 pw;
      pw[0] = (short)f2bf(e0);
      pw[1] = (short)f2bf(e1);
      pw[2] = (short)f2bf(e2);
      pw[3] = (short)f2bf(e3);
      *(bf16x4*)(Pb + ((t - 1) & 1) * 4096 + eq * 64 + ec * 8) = pw;
    }

    // ---- PV(t-2): all 64 rows x e [64w,+64), P from Pb[(t-2)&1] (== t&1)
    if (t >= 2) {
      const unsigned char* pb = Pb + (t & 1) * 4096;
      bf16x8 pa[4];
#pragma unroll
      for (int rf = 0; rf < 4; ++rf)
        pa[rf] = *(const bf16x8*)(pb + (16 * rf + l15) * 64 + g * 16);
      __builtin_amdgcn_s_setprio(1);
#pragma unroll
      for (int cf = 0; cf < 4; ++cf)
#pragma unroll
        for (int rf = 0; rf < 4; ++rf)
          acc[rf][cf] = __builtin_amdgcn_mfma_f32_16x16x32_bf16(pa[rf], bv[cf], acc[rf][cf], 0, 0, 0);
      __builtin_amdgcn_s_setprio(0);
    }
  }

  // ---- epilogue: lsum reduce (over ec lanes), publish, normalize + residual
  {
    float r = lsum_reg;
    r += __shfl_xor(r, 1, 64);
    r += __shfl_xor(r, 2, 64);
    r += __shfl_xor(r, 4, 64);
    if (ec == 0) lsumB[eq] = r;
  }
  __syncthreads();
#pragma unroll
  for (int rf = 0; rf < 4; ++rf)
#pragma unroll
    for (int j = 0; j < 4; ++j) {
      int qq = 16 * rf + 4 * g + j;
      float inv = 1.0f / lsumB[qq];
      int row = qbase + qq;
#pragma unroll
      for (int cf = 0; cf < 4; ++cf) {
        int col = 64 * w + 16 * cf + l15;
        size_t idx = (size_t)row * N_EMBED + col;
        out[idx] = acc[rf][cf][j] * inv + xf[idx];
      }
    }
}

extern "C" void kernel_launch(void* const* d_in, const int* in_sizes, int n_in,
                              void* d_out, int out_size, void* d_ws, size_t ws_size,
                              hipStream_t stream) {
  const float* x = (const float*)d_in[0];        // [8,2048,512] f32
  const float* lin_w = (const float*)d_in[1];    // [16384,512] f32
  const float* lin_b = (const float*)d_in[2];    // [16384] f32
  const float* value_w = (const float*)d_in[3];  // [16384,512] f32
  float* outp = (float*)d_out;

  unsigned short* xb = (unsigned short*)d_ws;                        // 16MB
  unsigned short* wb = (unsigned short*)((char*)d_ws + (16 << 20));  // 16MB
  unsigned short* vt = (unsigned short*)((char*)d_ws + (32 << 20));  // 16MB

  const int n8 = (N_TOKEN * N_EMBED) / 8;  // 1048576
  cvt_bf16_kernel<<<n8 / 256, 256, 0, stream>>>(x, xb, n8);
  cvt_bf16_kernel<<<n8 / 256, 256, 0, stream>>>(lin_w, wb, n8);
  transpose_cvt_kernel<<<dim3(N_TOKEN / 64, N_EMBED / 64), 256, 0, stream>>>(value_w, vt);
  flash4_kernel<<<N_TOKEN / QBLK, 512, 0, stream>>>(xb, wb, vt, lin_b, x, outp);
}